// Round 12
// baseline (265.173 us; speedup 1.0000x reference)
//
#include <hip/hip_runtime.h>

// Fused attention block (b=2, n=2048, dim=256, heads=8, inner=16384, d_head=2048)
// LOW-RANK: S_h = xn M_h xn^T (M_h = Wq_h^T Wk_h), Zt_h = N_h xn^T (N_h = Wo_h Wv_h).
// R22: minimal-delta retry after two infra failures (R20/R21 never ran).
//  - gemm_w: split-K x8 (K-chunk 256), dim3(2,2,128) = 512 blocks -> 2 blocks/CU
//    (was 256 blocks = 1/CU = 1 wave/SIMD, zero TLP). Only substantive change.
//  - gemm_yz: R16-measured config restored (dim3(16,16,4), launch_bounds(256,3);
//    48KB LDS caps at 3 blocks/CU -- R20's (256,4) was unachievable: 4x48KB>160KB).
//  - attn_fused: R19 verbatim (plateaued ~107us across 3 sync structures).
// prep/cast/hreduce unchanged.

typedef unsigned short u16;
typedef unsigned int u32;
typedef __bf16 bf16x8 __attribute__((ext_vector_type(8)));
typedef float f32x4 __attribute__((ext_vector_type(4)));

__device__ __forceinline__ u16 f2bf(float f) {
    u32 u = __builtin_bit_cast(u32, f);
    u += 0x7fffu + ((u >> 16) & 1u);   // RNE; inputs finite
    return (u16)(u >> 16);
}

#define GLDS16(G, L)                                                                  \
    __builtin_amdgcn_global_load_lds((const __attribute__((address_space(1))) u32*)(G), \
                                     (__attribute__((address_space(3))) u32*)(L), 16, 0, 0)

template <int N> __device__ __forceinline__ void vm_wait() {
    asm volatile("s_waitcnt vmcnt(%0)" :: "n"(N) : "memory");
}
__device__ __forceinline__ void lgk0() {
    asm volatile("s_waitcnt lgkmcnt(0)" ::: "memory");
}
__device__ __forceinline__ void bar() {
    __builtin_amdgcn_s_barrier();
    __builtin_amdgcn_sched_barrier(0);
}

// ---------------------------------------------------------------------------
// Shared GEMM core: C[m,n] (+)= sum_k A[m,k]*B[n,k] for one 128x128 tile at
// (bm, bn). Triple-buffered LDS (caller-provided 3x8KB ldsA/ldsB), issue
// distance 2, counted vmcnt, one barrier per K-step.
// ---------------------------------------------------------------------------
template <typename OutT, bool ATOMIC>
__device__ __forceinline__ void gemm_core(
    const u16* __restrict__ A, const u16* __restrict__ B, OutT* __restrict__ C,
    int K, int lda, int ldb, int ldc, int bm, int bn,
    u16* __restrict__ ldsA, u16* __restrict__ ldsB)
{
    const int t = threadIdx.x;
    const int w = t >> 6, l = t & 63;
    const int wm = w >> 1, wn = w & 1;
    const int lr = l & 15, lk = l >> 4;
    const int sw = lk ^ ((lr >> 1) & 3);

    const int m0 = t >> 2, s0 = t & 3;
    const int c0 = s0 ^ ((m0 >> 1) & 3);
    const int m1 = 64 + m0;
    const int c1 = s0 ^ ((m1 >> 1) & 3);
    const int o0 = (t & ~63) * 8;
    const int o1 = (256 + (t & ~63)) * 8;

    const u16* gA0 = A + (size_t)(bm + m0) * lda + c0 * 8;
    const u16* gA1 = A + (size_t)(bm + m1) * lda + c1 * 8;
    const u16* gB0 = B + (size_t)(bn + m0) * ldb + c0 * 8;
    const u16* gB1 = B + (size_t)(bn + m1) * ldb + c1 * 8;

    f32x4 acc[4][4];
#pragma unroll
    for (int i = 0; i < 4; ++i)
#pragma unroll
        for (int j = 0; j < 4; ++j)
            acc[i][j] = f32x4{0.f, 0.f, 0.f, 0.f};

    const int nk = K >> 5;

    GLDS16(gA0, ldsA + o0); GLDS16(gA1, ldsA + o1);
    GLDS16(gB0, ldsB + o0); GLDS16(gB1, ldsB + o1);
    gA0 += 32; gA1 += 32; gB0 += 32; gB1 += 32;
    GLDS16(gA0, ldsA + 4096 + o0); GLDS16(gA1, ldsA + 4096 + o1);
    GLDS16(gB0, ldsB + 4096 + o0); GLDS16(gB1, ldsB + 4096 + o1);
    gA0 += 32; gA1 += 32; gB0 += 32; gB1 += 32;

    int cur = 0, wsl = 2;
    for (int kt = 0; kt < nk - 1; ++kt) {
        vm_wait<4>(); bar();
        if (kt + 2 < nk) {
            GLDS16(gA0, ldsA + wsl * 4096 + o0); GLDS16(gA1, ldsA + wsl * 4096 + o1);
            GLDS16(gB0, ldsB + wsl * 4096 + o0); GLDS16(gB1, ldsB + wsl * 4096 + o1);
            gA0 += 32; gA1 += 32; gB0 += 32; gB1 += 32;
        }
        bf16x8 av[4], bv[4];
#pragma unroll
        for (int i = 0; i < 4; ++i) {
            av[i] = *(const bf16x8*)&ldsA[cur * 4096 + (wm * 64 + i * 16 + lr) * 32 + sw * 8];
            bv[i] = *(const bf16x8*)&ldsB[cur * 4096 + (wn * 64 + i * 16 + lr) * 32 + sw * 8];
        }
        __builtin_amdgcn_s_setprio(1);
#pragma unroll
        for (int i = 0; i < 4; ++i)
#pragma unroll
            for (int j = 0; j < 4; ++j)
                acc[i][j] = __builtin_amdgcn_mfma_f32_16x16x32_bf16(av[i], bv[j], acc[i][j], 0, 0, 0);
        __builtin_amdgcn_s_setprio(0);
        cur = (cur == 2) ? 0 : cur + 1;
        wsl = (wsl == 2) ? 0 : wsl + 1;
    }
    vm_wait<0>(); bar();
    {
        bf16x8 av[4], bv[4];
#pragma unroll
        for (int i = 0; i < 4; ++i) {
            av[i] = *(const bf16x8*)&ldsA[cur * 4096 + (wm * 64 + i * 16 + lr) * 32 + sw * 8];
            bv[i] = *(const bf16x8*)&ldsB[cur * 4096 + (wn * 64 + i * 16 + lr) * 32 + sw * 8];
        }
        __builtin_amdgcn_s_setprio(1);
#pragma unroll
        for (int i = 0; i < 4; ++i)
#pragma unroll
            for (int j = 0; j < 4; ++j)
                acc[i][j] = __builtin_amdgcn_mfma_f32_16x16x32_bf16(av[i], bv[j], acc[i][j], 0, 0, 0);
        __builtin_amdgcn_s_setprio(0);
    }

#pragma unroll
    for (int i = 0; i < 4; ++i) {
        const int row0 = bm + wm * 64 + i * 16 + lk * 4;
#pragma unroll
        for (int j = 0; j < 4; ++j) {
            const int col = bn + wn * 64 + j * 16 + lr;
#pragma unroll
            for (int r = 0; r < 4; ++r) {
                const size_t idx = (size_t)(row0 + r) * ldc + col;
                const float v = acc[i][j][r];
                if constexpr (ATOMIC) {
                    atomicAdd(&C[idx], v);
                } else if constexpr (sizeof(OutT) == 2) {
                    C[idx] = (OutT)f2bf(v);
                } else {
                    C[idx] = (OutT)v;
                }
            }
        }
    }
}

// Both weight GEMMs in one dispatch, split-K x8 + fp32 atomics. dim3(2,2,128).
// z: zh = z&7 (head), q = z>>3, which = q&1 (0: Mt, 1: Nb), kc = q>>1 (0..7).
__global__ void __launch_bounds__(256, 3) gemm_w(
    const u16* __restrict__ wkt, const u16* __restrict__ wqt,
    const u16* __restrict__ wo, const u16* __restrict__ wvt,
    float* __restrict__ MtF)
{
    __shared__ u16 ldsA[3][4096];
    __shared__ u16 ldsB[3][4096];
    const int z = blockIdx.z;
    const int zh = z & 7;
    const int q = z >> 3;
    const int which = q & 1;
    const int kc = q >> 1;
    const u16* A; const u16* B; float* C; int lda;
    if (which == 0) {
        A = wkt + (size_t)zh * 524288 + kc * 256; lda = 2048;
        B = wqt + (size_t)zh * 524288 + kc * 256;
        C = MtF + (size_t)zh * 65536;
    } else {
        A = wo + (size_t)zh * 2048 + kc * 256;    lda = 16384;
        B = wvt + (size_t)zh * 524288 + kc * 256;
        C = MtF + 524288 + (size_t)zh * 65536;
    }
    gemm_core<float, true>(A, B, C, 256, lda, 2048, 256,
                           blockIdx.y * 128, blockIdx.x * 128,
                           &ldsA[0][0], &ldsB[0][0]);
}

// Y-GEMM (2 halves) + Zt-GEMM (2 batches). dim3(16,16,4) = 1024 blocks, 3/CU.
__global__ void __launch_bounds__(256, 3) gemm_yz(
    const u16* __restrict__ xn, const u16* __restrict__ Mt,
    const u16* __restrict__ Nb, u16* __restrict__ Y, u16* __restrict__ Zt)
{
    __shared__ u16 ldsA[3][4096];
    __shared__ u16 ldsB[3][4096];
    const int z = blockIdx.z;
    const u16* A; const u16* B; u16* C;
    if (z < 2) {
        A = xn + (size_t)z * 524288;
        B = Mt;
        C = Y + (size_t)z * 4194304;
    } else {
        const int b = z - 2;
        A = Nb;
        B = xn + (size_t)b * 524288;
        C = Zt + (size_t)b * 4194304;
    }
    gemm_core<u16, false>(A, B, C, 256, 256, 256, 2048,
                          blockIdx.y * 128, blockIdx.x * 128,
                          &ldsA[0][0], &ldsB[0][0]);
}

// ---------------------------------------------------------------------------
// Fused prologue: tcast3 (0..3071) + cast_wo (3072..7167) + ln (7168..8191) +
// zero MtF (8192..9215).
// ---------------------------------------------------------------------------
__global__ void __launch_bounds__(256) prep_kernel(
    const float* __restrict__ x, const float* __restrict__ g,
    const float* __restrict__ Wq, const float* __restrict__ Wk,
    const float* __restrict__ Wv, const float* __restrict__ Wo,
    u16* __restrict__ wqkv, u16* __restrict__ wo_b,
    u16* __restrict__ xn, float* __restrict__ MtF)
{
    __shared__ u16 tile[64][66];
    const int bid = blockIdx.x;
    const int t = threadIdx.x;
    if (bid < 3072) {
        const int bx = bid & 31, by = (bid >> 5) & 3, z = bid >> 7;
        const int wsel = z >> 3, h = z & 7;
        const float* src = (wsel == 0) ? Wq : (wsel == 1) ? Wk : Wv;
        const float scale = (wsel == 0) ? 0.125f : 1.0f;
        u16* d = wqkv + (size_t)wsel * 4194304;
        const int d0 = bx * 64;
        const int a0 = by * 64;
        const int c = t & 63, r0 = t >> 6;
#pragma unroll
        for (int rr = 0; rr < 16; ++rr) {
            const int r = r0 + rr * 4;
            tile[r][c] = f2bf(src[((size_t)h * 2048 + d0 + r) * 256 + a0 + c] * scale);
        }
        __syncthreads();
#pragma unroll
        for (int rr = 0; rr < 16; ++rr) {
            const int r = r0 + rr * 4;
            d[((size_t)h * 256 + a0 + r) * 2048 + d0 + c] = tile[c][r];
        }
    } else if (bid < 7168) {
        const size_t i = (size_t)(bid - 3072) * 256 + t;
        const float4 v = ((const float4*)Wo)[i];
        ushort4 o4;
        o4.x = f2bf(v.x); o4.y = f2bf(v.y); o4.z = f2bf(v.z); o4.w = f2bf(v.w);
        ((ushort4*)wo_b)[i] = o4;
    } else if (bid < 8192) {
        const size_t row = (size_t)(bid - 7168) * 4 + (t >> 6);
        const int l = t & 63;
        const float4 v = ((const float4*)(x + row * 256))[l];
        float s = v.x + v.y + v.z + v.w;
        float qq = v.x * v.x + v.y * v.y + v.z * v.z + v.w * v.w;
#pragma unroll
        for (int o = 32; o > 0; o >>= 1) {
            s += __shfl_xor(s, o, 64);
            qq += __shfl_xor(qq, o, 64);
        }
        const float mu = s * (1.0f / 256.0f);
        const float var = qq * (1.0f / 256.0f) - mu * mu;
        const float rs = rsqrtf(var + 1e-5f);
        const float4 gg = ((const float4*)g)[l];
        ushort4 o4;
        o4.x = f2bf((v.x - mu) * rs * (gg.x + 1.0f));
        o4.y = f2bf((v.y - mu) * rs * (gg.y + 1.0f));
        o4.z = f2bf((v.z - mu) * rs * (gg.z + 1.0f));
        o4.w = f2bf((v.w - mu) * rs * (gg.w + 1.0f));
        ((ushort4*)(xn + row * 256))[l] = o4;
    } else {
        const size_t i = (size_t)(bid - 8192) * 256 + t;
        ((float4*)MtF)[i] = float4{0.f, 0.f, 0.f, 0.f};
    }
}

// ---------------------------------------------------------------------------
// Flash-fused attention (R19 verbatim), BK=64 S-steps. 512 blocks, 2 blk/CU.
// LDS 80KB exact: ldsB 2x16KB | ldsZ 2x16KB (prologue: Y) | Pl 16KB swizzled.
// ---------------------------------------------------------------------------
__global__ void __launch_bounds__(256, 2) attn_fused(
    const u16* __restrict__ Y, const u16* __restrict__ xn,
    const u16* __restrict__ Zt, float* __restrict__ opart)
{
    __shared__ u16 ldsB[2][8192];      // 32 KB: slot x (sub0 | sub1)
    __shared__ u16 ldsZ[2][8192];      // 32 KB (prologue: Y tile spans both)
    __shared__ u16 Pl[8192];           // 16 KB swizzled

    const int wgid = blockIdx.x + 32 * blockIdx.y;
    const int xcd = wgid & 7;
    const int p = wgid >> 3;
    const int hb = 2 * xcd + (p & 1);
    const int i0 = (p >> 1) * 64;
    const int h = hb >> 1, b = hb & 1;

    const int t = threadIdx.x;
    const int w = t >> 6, l = t & 63;
    const int wm = w >> 1, wn = w & 1;
    const int lr = l & 15, lk = l >> 4;
    const int sw = lk ^ ((lr >> 1) & 3);

    const u16* Yb = Y + (size_t)(b * 2048 + i0) * 2048 + h * 256;
    const u16* xb = xn + (size_t)b * 2048 * 256;
    const u16* Zb = Zt + (size_t)b * 4194304 + (size_t)h * 524288;

    const int m0 = t >> 2, s0 = t & 3;
    const int c0 = s0 ^ ((m0 >> 1) & 3);
    const int m1 = 64 + m0;
    const int c1 = s0 ^ ((m1 >> 1) & 3);
    const int oB0 = (t & ~63) * 8;
    const int oB1 = (256 + (t & ~63)) * 8;

    const u16 *gZ0, *gZ1, *gZ2, *gZ3;
    const int oZ0 = (t & ~63) * 8;
    const int oZ1 = (256 + (t & ~63)) * 8;
    const int oZ2 = (512 + (t & ~63)) * 8;
    const int oZ3 = (768 + (t & ~63)) * 8;
    {
        const int q0 = t, q1 = 256 + t, q2 = 512 + t, q3 = 768 + t;
        const int mz0 = q0 >> 2, mz1 = q1 >> 2, mz2 = q2 >> 2, mz3 = q3 >> 2;
        const int cz0 = (q0 & 3) ^ ((mz0 >> 1) & 3);
        const int cz1 = (q1 & 3) ^ ((mz1 >> 1) & 3);
        const int cz2 = (q2 & 3) ^ ((mz2 >> 1) & 3);
        const int cz3 = (q3 & 3) ^ ((mz3 >> 1) & 3);
        gZ0 = Zb + (size_t)mz0 * 2048 + cz0 * 8;
        gZ1 = Zb + (size_t)mz1 * 2048 + cz1 * 8;
        gZ2 = Zb + (size_t)mz2 * 2048 + cz2 * 8;
        gZ3 = Zb + (size_t)mz3 * 2048 + cz3 * 8;
    }

#define ISSUE_B_HALF(JBASE, KK, SLOT, SUB)                                            \
    GLDS16(JBASE + (size_t)m0 * 256 + (KK) * 32 + c0 * 8, &ldsB[SLOT][(SUB) * 4096 + oB0]); \
    GLDS16(JBASE + (size_t)m1 * 256 + (KK) * 32 + c1 * 8, &ldsB[SLOT][(SUB) * 4096 + oB1])

#define ISSUE_B2(JBASE, K0, K1, SLOT)                                                 \
    ISSUE_B_HALF(JBASE, K0, SLOT, 0); ISSUE_B_HALF(JBASE, K1, SLOT, 1)

#define ISSUE_Z(OFF, ZBUF)                                                            \
    GLDS16(gZ0 + (OFF), &ldsZ[ZBUF][oZ0]);                                            \
    GLDS16(gZ1 + (OFF), &ldsZ[ZBUF][oZ1]);                                            \
    GLDS16(gZ2 + (OFF), &ldsZ[ZBUF][oZ2]);                                            \
    GLDS16(gZ3 + (OFF), &ldsZ[ZBUF][oZ3])

    // ---- prologue: Y i-tile (32KB) into ldsZ; B(jt0, s0) into ldsB[0] ----
    u16* ldsY = &ldsZ[0][0];
#pragma unroll
    for (int pp = 0; pp < 8; ++pp) {
        const int q = pp * 256 + t;
        const int kt = q >> 8, qq = q & 255;
        const int m = qq >> 2, s = qq & 3;
        const int c = s ^ ((m >> 1) & 3);
        GLDS16(Yb + (size_t)m * 2048 + kt * 32 + c * 8,
               &ldsY[(pp * 256 + (t & ~63)) * 8]);
    }
    ISSUE_B2(xb, 0, 1, 0);
    vm_wait<4>();                      // Y(8) retired; B(4) in flight
    bar();

    bf16x8 yr[8][2];
#pragma unroll
    for (int kt = 0; kt < 8; ++kt)
#pragma unroll
        for (int i = 0; i < 2; ++i)
            yr[kt][i] = *(const bf16x8*)&ldsY[kt * 2048 + (wm * 32 + i * 16 + lr) * 32 + sw * 8];
    lgk0();
    bar();                             // yr reads done before ldsZ overwrite

    f32x4 acc_o[2][8];
#pragma unroll
    for (int i = 0; i < 2; ++i)
#pragma unroll
        for (int j = 0; j < 8; ++j)
            acc_o[i][j] = f32x4{0.f, 0.f, 0.f, 0.f};
    float lsum[8];
#pragma unroll
    for (int i = 0; i < 8; ++i) lsum[i] = 0.f;

#define S_STEP2(KT0, KT1, SLOT, ISSUE)                                                \
    {                                                                                 \
        vm_wait<0>(); bar();                                                          \
        ISSUE;                                                                        \
        {                                                                             \
            bf16x8 bv[4];                                                             \
            _Pragma("unroll")                                                         \
            for (int j = 0; j < 4; ++j)                                               \
                bv[j] = *(const bf16x8*)&ldsB[SLOT][(wn * 64 + j * 16 + lr) * 32 + sw * 8]; \
            __builtin_amdgcn_s_setprio(1);                                            \
            _Pragma("unroll")                                                         \
            for (int j = 0; j < 4; ++j) {                                             \
                acc_s[0][j] = __builtin_amdgcn_mfma_f32_16x16x32_bf16(yr[KT0][0], bv[j], acc_s[0][j], 0, 0, 0); \
                acc_s[1][j] = __builtin_amdgcn_mfma_f32_16x16x32_bf16(yr[KT0][1], bv[j], acc_s[1][j], 0, 0, 0); \
            }                                                                         \
            __builtin_amdgcn_s_setprio(0);                                            \
        }                                                                             \
        {                                                                             \
            bf16x8 bv[4];                                                             \
            _Pragma("unroll")                                                         \
            for (int j = 0; j < 4; ++j)                                               \
                bv[j] = *(const bf16x8*)&ldsB[SLOT][4096 + (wn * 64 + j * 16 + lr) * 32 + sw * 8]; \
            __builtin_amdgcn_s_setprio(1);                                            \
            _Pragma("unroll")                                                         \
            for (int j = 0; j < 4; ++j) {                                             \
                acc_s[0][j] = __builtin_amdgcn_mfma_f32_16x16x32_bf16(yr[KT1][0], bv[j], acc_s[0][j], 0, 0, 0); \
                acc_s[1][j] = __builtin_amdgcn_mfma_f32_16x16x32_bf16(yr[KT1][1], bv[j], acc_s[1][j], 0, 0, 0); \
            }                                                                         \
            __builtin_amdgcn_s_setprio(0);                                            \
        }                                                                             \
    }

#define PV_STEP(KT, VMC, ISSUE)                                                       \
    {                                                                                 \
        vm_wait<VMC>(); bar();                                                        \
        ISSUE;                                                                        \
        const int swz = (lr & 7) * 8;                                                 \
        bf16x8 av0 = *(const bf16x8*)&Pl[(wm * 32 + lr) * 128 + (((KT) * 32 + lk * 8) ^ swz)];      \
        bf16x8 av1 = *(const bf16x8*)&Pl[(wm * 32 + 16 + lr) * 128 + (((KT) * 32 + lk * 8) ^ swz)]; \
        __builtin_amdgcn_s_setprio(1);                                                \
        _Pragma("unroll")                                                             \
        for (int jf = 0; jf < 8; ++jf) {                                              \
            const bf16x8 bz = *(const bf16x8*)&ldsZ[(KT) & 1][(wn * 128 + jf * 16 + lr) * 32 + sw * 8]; \
            acc_o[0][jf] = __builtin_amdgcn_mfma_f32_16x16x32_bf16(av0, bz, acc_o[0][jf], 0, 0, 0);   \
            acc_o[1][jf] = __builtin_amdgcn_mfma_f32_16x16x32_bf16(av1, bz, acc_o[1][jf], 0, 0, 0);   \
        }                                                                             \
        __builtin_amdgcn_s_setprio(0);                                                \
    }

    for (int jt = 0; jt < 16; ++jt) {
        const int j0 = jt * 128;
        const u16* xbj = xb + (size_t)j0 * 256;
        const u16* xbn = xb + (size_t)(((jt + 1) & 15) * 128) * 256;  // wrap: dummy

        f32x4 acc_s[2][4];
#pragma unroll
        for (int i = 0; i < 2; ++i)
#pragma unroll
            for (int j = 0; j < 4; ++j)
                acc_s[i][j] = f32x4{0.f, 0.f, 0.f, 0.f};

        // S phase: 4 merged steps. queues: entering S0: [B_s0(4)]
        S_STEP2(0, 1, 0, ISSUE_B2(xbj, 2, 3, 1))
        S_STEP2(2, 3, 1, ISSUE_B2(xbj, 4, 5, 0))
        S_STEP2(4, 5, 0, ISSUE_B2(xbj, 6, 7, 1))
        S_STEP2(6, 7, 1, ISSUE_Z(j0, 0))
        ISSUE_Z(j0 + 32, 1);           // in-flight entering exp: [Z0(4), Z1(4)]

        // exp + l partials + P -> swizzled Pl[row][col ^ ((row&7)*8)]
#pragma unroll
        for (int i = 0; i < 2; ++i)
#pragma unroll
            for (int j = 0; j < 4; ++j)
#pragma unroll
                for (int r = 0; r < 4; ++r) {
                    const int row = wm * 32 + i * 16 + lk * 4 + r;
                    const int col = wn * 64 + j * 16 + lr;
                    const float e = __expf(acc_s[i][j][r]);
                    lsum[i * 4 + r] += e;
                    Pl[row * 128 + (col ^ ((row & 7) * 8))] = f2bf(e);
                }
        lgk0();                        // Pl writes done; PV0's bar publishes

        // PV queues: entering PV0: [Z0(4), Z1(4)]
        PV_STEP(0, 4, ((void)0))
        PV_STEP(1, 0, ISSUE_Z(j0 + 64, 0))
        PV_STEP(2, 0, ISSUE_Z(j0 + 96, 1); ISSUE_B_HALF(xbn, 0, 0, 0))
        PV_STEP(3, 2, ISSUE_B_HALF(xbn, 1, 0, 1))   // [Z3(4),Bh(2)] -> keep Bh
    }

    // ---- finalize l (bar: all PV3 Pl reads done before aliasing) ----
    bar();
    float* l_lds = (float*)Pl;
    if (t < 64) l_lds[t] = 0.f;
    __syncthreads();
#pragma unroll
    for (int i = 0; i < 2; ++i)
#pragma unroll
        for (int r = 0; r < 4; ++r) {
            float s = lsum[i * 4 + r];
            s += __shfl_xor(s, 1, 64);
            s += __shfl_xor(s, 2, 64);
            s += __shfl_xor(s, 4, 64);
            s += __shfl_xor(s, 8, 64);
            if (lr == 0) atomicAdd(&l_lds[wm * 32 + i * 16 + lk * 4 + r], s);
        }
    __syncthreads();

    // ---- scale by 1/l, plain-store per-head partial ----
    float* oh = opart + (size_t)h * 1048576;
#pragma unroll
    for (int i = 0; i < 2; ++i)
#pragma unroll
        for (int r = 0; r < 4; ++r) {
            const int row = wm * 32 + i * 16 + lk * 4 + r;
            const float rl = 1.0f / l_lds[row];
            float* orow = oh + (size_t)(b * 2048 + i0 + row) * 256 + wn * 128;
#pragma unroll
            for (int jf = 0; jf < 8; ++jf)
                orow[jf * 16 + lr] = acc_o[i][jf][r] * rl;
        }
}

// ---------------------------------------------------------------------------
// Head reduction: out[i] = sum_h opart[h][i].
// ---------------------------------------------------------------------------
__global__ void __launch_bounds__(256) hreduce_kernel(const float* __restrict__ opart,
                                                      float* __restrict__ out)
{
    const size_t i = (size_t)blockIdx.x * 256 + threadIdx.x;
    float4 s = ((const float4*)opart)[i];
#pragma unroll
    for (int h = 1; h < 8; ++h) {
        const float4 v = ((const float4*)(opart + (size_t)h * 1048576))[i];
        s.x += v.x; s.y += v.y; s.z += v.z; s.w += v.w;
    }
    ((float4*)out)[i] = s;
}

__global__ void __launch_bounds__(256) cast_bf16_kernel(const float* __restrict__ src,
                                                        u16* __restrict__ dst, float scale)
{
    const size_t i = (size_t)blockIdx.x * 256 + threadIdx.x;
    const float4 v = ((const float4*)src)[i];
    ushort4 o4;
    o4.x = f2bf(v.x * scale);
    o4.y = f2bf(v.y * scale);
    o4.z = f2bf(v.z * scale);
    o4.w = f2bf(v.w * scale);
    ((ushort4*)dst)[i] = o4;
}

extern "C" void kernel_launch(void* const* d_in, const int* in_sizes, int n_in,
                              void* d_out, int out_size, void* d_ws, size_t ws_size,
                              hipStream_t stream)
{
    (void)in_sizes; (void)n_in; (void)ws_size; (void)out_size;
    const float* x     = (const float*)d_in[0];
    const float* gamma = (const float*)d_in[1];
    const float* Wq    = (const float*)d_in[2];
    const float* Wk    = (const float*)d_in[3];
    const float* Wv    = (const float*)d_in[4];
    const float* Wo    = (const float*)d_in[5];
    float* out = (float*)d_out;

    char* ws = (char*)d_ws;
    const size_t MB = 1048576;
    u16* wqt   = (u16*)(ws);             // [3][8][256][2048] bf16 (SCALE folded in Wq)
    u16* wkt   = (u16*)(ws + 8 * MB);
    u16* wvt   = (u16*)(ws + 16 * MB);
    u16* wo    = (u16*)(ws + 24 * MB);   // [256][16384] bf16
    u16* xn    = (u16*)(ws + 32 * MB);   // [4096][256] bf16
    u16* Mt    = (u16*)(ws + 34 * MB);   // [8*256][256] bf16
    u16* Nb    = (u16*)(ws + 35 * MB);   // [8*256][256] bf16
    float* MtF = (float*)(ws + 36 * MB); // fp32 split-K accum: Mt (2MB) + Nb (2MB)
    u16* Y     = (u16*)(ws + 44 * MB);   // [4096][2048] bf16
    u16* Zt    = (u16*)(ws + 60 * MB);   // [2][2048][2048] bf16
    float* opart = (float*)(ws);         // [8][4096][256] fp32 (reuses 0..32MB)

    // 1. fused prologue: tcast3 + cast_wo + ln + zero(MtF)
    prep_kernel<<<9216, 256, 0, stream>>>(x, gamma, Wq, Wk, Wv, Wo, wqt, wo, xn, MtF);

    // 2. both weight GEMMs (split-K x8, fp32 atomics, 512 blocks = 2/CU)
    gemm_w<<<dim3(2, 2, 128), 256, 0, stream>>>(wkt, wqt, wo, wvt, MtF);

    // 3. cast MtF+NbF -> Mt+Nb bf16
    cast_bf16_kernel<<<1024, 256, 0, stream>>>(MtF, Mt, 1.0f);

    // 4. Y = xn.Mt^T and Zt = Nb.xn^T
    gemm_yz<<<dim3(16, 16, 4), 256, 0, stream>>>(xn, Mt, Nb, Y, Zt);

    // 5. fused S -> softmax -> PV -> per-head partial stores
    attn_fused<<<dim3(32, 16), 256, 0, stream>>>(Y, xn, Zt, opart);

    // 6. head-sum reduction
    hreduce_kernel<<<1024, 256, 0, stream>>>(opart, out);
}

// Round 13
// 250.951 us; speedup vs baseline: 1.0567x; 1.0567x over previous
//
#include <hip/hip_runtime.h>

// Fused attention block (b=2, n=2048, dim=256, heads=8, inner=16384, d_head=2048)
// LOW-RANK: S_h = xn M_h xn^T (M_h = Wq_h^T Wk_h), Zt_h = N_h xn^T (N_h = Wo_h Wv_h).
// R23: (1) gemm_w reverted to measured-best split-K x4 (R16: 253.8us); R22's
// split-K x8 was -11us (2x atomics + unamortized prologue). (2) ln co-dispatched
// as extra z-slices of gemm_w (z>=64): gemm_w runs 1 block/CU = 1 wave/SIMD with
// zero TLP, so ln's independent 1024 light blocks fill the idle wave slots for
// free. prep drops ln (8192 blocks: tcast3/cast_wo/zero). attn_fused R19 verbatim.

typedef unsigned short u16;
typedef unsigned int u32;
typedef __bf16 bf16x8 __attribute__((ext_vector_type(8)));
typedef float f32x4 __attribute__((ext_vector_type(4)));

__device__ __forceinline__ u16 f2bf(float f) {
    u32 u = __builtin_bit_cast(u32, f);
    u += 0x7fffu + ((u >> 16) & 1u);   // RNE; inputs finite
    return (u16)(u >> 16);
}

#define GLDS16(G, L)                                                                  \
    __builtin_amdgcn_global_load_lds((const __attribute__((address_space(1))) u32*)(G), \
                                     (__attribute__((address_space(3))) u32*)(L), 16, 0, 0)

template <int N> __device__ __forceinline__ void vm_wait() {
    asm volatile("s_waitcnt vmcnt(%0)" :: "n"(N) : "memory");
}
__device__ __forceinline__ void lgk0() {
    asm volatile("s_waitcnt lgkmcnt(0)" ::: "memory");
}
__device__ __forceinline__ void bar() {
    __builtin_amdgcn_s_barrier();
    __builtin_amdgcn_sched_barrier(0);
}

// ---------------------------------------------------------------------------
// Shared GEMM core: C[m,n] (+)= sum_k A[m,k]*B[n,k] for one 128x128 tile at
// (bm, bn). Triple-buffered LDS (caller-provided 3x8KB ldsA/ldsB), issue
// distance 2, counted vmcnt, one barrier per K-step.
// ---------------------------------------------------------------------------
template <typename OutT, bool ATOMIC>
__device__ __forceinline__ void gemm_core(
    const u16* __restrict__ A, const u16* __restrict__ B, OutT* __restrict__ C,
    int K, int lda, int ldb, int ldc, int bm, int bn,
    u16* __restrict__ ldsA, u16* __restrict__ ldsB)
{
    const int t = threadIdx.x;
    const int w = t >> 6, l = t & 63;
    const int wm = w >> 1, wn = w & 1;
    const int lr = l & 15, lk = l >> 4;
    const int sw = lk ^ ((lr >> 1) & 3);

    const int m0 = t >> 2, s0 = t & 3;
    const int c0 = s0 ^ ((m0 >> 1) & 3);
    const int m1 = 64 + m0;
    const int c1 = s0 ^ ((m1 >> 1) & 3);
    const int o0 = (t & ~63) * 8;
    const int o1 = (256 + (t & ~63)) * 8;

    const u16* gA0 = A + (size_t)(bm + m0) * lda + c0 * 8;
    const u16* gA1 = A + (size_t)(bm + m1) * lda + c1 * 8;
    const u16* gB0 = B + (size_t)(bn + m0) * ldb + c0 * 8;
    const u16* gB1 = B + (size_t)(bn + m1) * ldb + c1 * 8;

    f32x4 acc[4][4];
#pragma unroll
    for (int i = 0; i < 4; ++i)
#pragma unroll
        for (int j = 0; j < 4; ++j)
            acc[i][j] = f32x4{0.f, 0.f, 0.f, 0.f};

    const int nk = K >> 5;

    GLDS16(gA0, ldsA + o0); GLDS16(gA1, ldsA + o1);
    GLDS16(gB0, ldsB + o0); GLDS16(gB1, ldsB + o1);
    gA0 += 32; gA1 += 32; gB0 += 32; gB1 += 32;
    GLDS16(gA0, ldsA + 4096 + o0); GLDS16(gA1, ldsA + 4096 + o1);
    GLDS16(gB0, ldsB + 4096 + o0); GLDS16(gB1, ldsB + 4096 + o1);
    gA0 += 32; gA1 += 32; gB0 += 32; gB1 += 32;

    int cur = 0, wsl = 2;
    for (int kt = 0; kt < nk - 1; ++kt) {
        vm_wait<4>(); bar();
        if (kt + 2 < nk) {
            GLDS16(gA0, ldsA + wsl * 4096 + o0); GLDS16(gA1, ldsA + wsl * 4096 + o1);
            GLDS16(gB0, ldsB + wsl * 4096 + o0); GLDS16(gB1, ldsB + wsl * 4096 + o1);
            gA0 += 32; gA1 += 32; gB0 += 32; gB1 += 32;
        }
        bf16x8 av[4], bv[4];
#pragma unroll
        for (int i = 0; i < 4; ++i) {
            av[i] = *(const bf16x8*)&ldsA[cur * 4096 + (wm * 64 + i * 16 + lr) * 32 + sw * 8];
            bv[i] = *(const bf16x8*)&ldsB[cur * 4096 + (wn * 64 + i * 16 + lr) * 32 + sw * 8];
        }
        __builtin_amdgcn_s_setprio(1);
#pragma unroll
        for (int i = 0; i < 4; ++i)
#pragma unroll
            for (int j = 0; j < 4; ++j)
                acc[i][j] = __builtin_amdgcn_mfma_f32_16x16x32_bf16(av[i], bv[j], acc[i][j], 0, 0, 0);
        __builtin_amdgcn_s_setprio(0);
        cur = (cur == 2) ? 0 : cur + 1;
        wsl = (wsl == 2) ? 0 : wsl + 1;
    }
    vm_wait<0>(); bar();
    {
        bf16x8 av[4], bv[4];
#pragma unroll
        for (int i = 0; i < 4; ++i) {
            av[i] = *(const bf16x8*)&ldsA[cur * 4096 + (wm * 64 + i * 16 + lr) * 32 + sw * 8];
            bv[i] = *(const bf16x8*)&ldsB[cur * 4096 + (wn * 64 + i * 16 + lr) * 32 + sw * 8];
        }
        __builtin_amdgcn_s_setprio(1);
#pragma unroll
        for (int i = 0; i < 4; ++i)
#pragma unroll
            for (int j = 0; j < 4; ++j)
                acc[i][j] = __builtin_amdgcn_mfma_f32_16x16x32_bf16(av[i], bv[j], acc[i][j], 0, 0, 0);
        __builtin_amdgcn_s_setprio(0);
    }

#pragma unroll
    for (int i = 0; i < 4; ++i) {
        const int row0 = bm + wm * 64 + i * 16 + lk * 4;
#pragma unroll
        for (int j = 0; j < 4; ++j) {
            const int col = bn + wn * 64 + j * 16 + lr;
#pragma unroll
            for (int r = 0; r < 4; ++r) {
                const size_t idx = (size_t)(row0 + r) * ldc + col;
                const float v = acc[i][j][r];
                if constexpr (ATOMIC) {
                    atomicAdd(&C[idx], v);
                } else if constexpr (sizeof(OutT) == 2) {
                    C[idx] = (OutT)f2bf(v);
                } else {
                    C[idx] = (OutT)v;
                }
            }
        }
    }
}

// Weight GEMMs (split-K x4, fp32 atomics; R16-measured best) + co-dispatched ln.
// grid dim3(2,2,320): z<64 = GEMM (zh=z&7, q=z>>3, which=q&1, kc=q>>1);
// z>=64 = layernorm, block id lb=(z-64)*4 + y*2+x, 4 rows/block (fills the
// idle wave slots of the 1-block/CU GEMM phase; data-independent).
__global__ void __launch_bounds__(256, 3) gemm_w(
    const u16* __restrict__ wkt, const u16* __restrict__ wqt,
    const u16* __restrict__ wo, const u16* __restrict__ wvt,
    float* __restrict__ MtF,
    const float* __restrict__ x, const float* __restrict__ g,
    u16* __restrict__ xn)
{
    __shared__ u16 ldsA[3][4096];
    __shared__ u16 ldsB[3][4096];
    const int z = blockIdx.z;
    const int t = threadIdx.x;
    if (z >= 64) {
        // layernorm: 4 rows/block, one per wave
        const int lb = (z - 64) * 4 + blockIdx.y * 2 + blockIdx.x;
        const size_t row = (size_t)lb * 4 + (t >> 6);
        const int l = t & 63;
        const float4 v = ((const float4*)(x + row * 256))[l];
        float s = v.x + v.y + v.z + v.w;
        float qq = v.x * v.x + v.y * v.y + v.z * v.z + v.w * v.w;
#pragma unroll
        for (int o = 32; o > 0; o >>= 1) {
            s += __shfl_xor(s, o, 64);
            qq += __shfl_xor(qq, o, 64);
        }
        const float mu = s * (1.0f / 256.0f);
        const float var = qq * (1.0f / 256.0f) - mu * mu;
        const float rs = rsqrtf(var + 1e-5f);
        const float4 gg = ((const float4*)g)[l];
        ushort4 o4;
        o4.x = f2bf((v.x - mu) * rs * (gg.x + 1.0f));
        o4.y = f2bf((v.y - mu) * rs * (gg.y + 1.0f));
        o4.z = f2bf((v.z - mu) * rs * (gg.z + 1.0f));
        o4.w = f2bf((v.w - mu) * rs * (gg.w + 1.0f));
        ((ushort4*)(xn + row * 256))[l] = o4;
        return;
    }
    const int zh = z & 7;
    const int q = z >> 3;
    const int which = q & 1;
    const int kc = q >> 1;
    const u16* A; const u16* B; float* C; int lda;
    if (which == 0) {
        A = wkt + (size_t)zh * 524288 + kc * 512; lda = 2048;
        B = wqt + (size_t)zh * 524288 + kc * 512;
        C = MtF + (size_t)zh * 65536;
    } else {
        A = wo + (size_t)zh * 2048 + kc * 512;    lda = 16384;
        B = wvt + (size_t)zh * 524288 + kc * 512;
        C = MtF + 524288 + (size_t)zh * 65536;
    }
    gemm_core<float, true>(A, B, C, 512, lda, 2048, 256,
                           blockIdx.y * 128, blockIdx.x * 128,
                           &ldsA[0][0], &ldsB[0][0]);
}

// Y-GEMM (2 halves) + Zt-GEMM (2 batches). dim3(16,16,4) = 1024 blocks, 3/CU.
__global__ void __launch_bounds__(256, 3) gemm_yz(
    const u16* __restrict__ xn, const u16* __restrict__ Mt,
    const u16* __restrict__ Nb, u16* __restrict__ Y, u16* __restrict__ Zt)
{
    __shared__ u16 ldsA[3][4096];
    __shared__ u16 ldsB[3][4096];
    const int z = blockIdx.z;
    const u16* A; const u16* B; u16* C;
    if (z < 2) {
        A = xn + (size_t)z * 524288;
        B = Mt;
        C = Y + (size_t)z * 4194304;
    } else {
        const int b = z - 2;
        A = Nb;
        B = xn + (size_t)b * 524288;
        C = Zt + (size_t)b * 4194304;
    }
    gemm_core<u16, false>(A, B, C, 256, 256, 256, 2048,
                          blockIdx.y * 128, blockIdx.x * 128,
                          &ldsA[0][0], &ldsB[0][0]);
}

// ---------------------------------------------------------------------------
// Fused prologue: tcast3 (0..3071) + cast_wo (3072..7167) + zero MtF (7168..8191).
// (ln moved into the gemm_w dispatch.)
// ---------------------------------------------------------------------------
__global__ void __launch_bounds__(256) prep_kernel(
    const float* __restrict__ Wq, const float* __restrict__ Wk,
    const float* __restrict__ Wv, const float* __restrict__ Wo,
    u16* __restrict__ wqkv, u16* __restrict__ wo_b,
    float* __restrict__ MtF)
{
    __shared__ u16 tile[64][66];
    const int bid = blockIdx.x;
    const int t = threadIdx.x;
    if (bid < 3072) {
        const int bx = bid & 31, by = (bid >> 5) & 3, z = bid >> 7;
        const int wsel = z >> 3, h = z & 7;
        const float* src = (wsel == 0) ? Wq : (wsel == 1) ? Wk : Wv;
        const float scale = (wsel == 0) ? 0.125f : 1.0f;
        u16* d = wqkv + (size_t)wsel * 4194304;
        const int d0 = bx * 64;
        const int a0 = by * 64;
        const int c = t & 63, r0 = t >> 6;
#pragma unroll
        for (int rr = 0; rr < 16; ++rr) {
            const int r = r0 + rr * 4;
            tile[r][c] = f2bf(src[((size_t)h * 2048 + d0 + r) * 256 + a0 + c] * scale);
        }
        __syncthreads();
#pragma unroll
        for (int rr = 0; rr < 16; ++rr) {
            const int r = r0 + rr * 4;
            d[((size_t)h * 256 + a0 + r) * 2048 + d0 + c] = tile[c][r];
        }
    } else if (bid < 7168) {
        const size_t i = (size_t)(bid - 3072) * 256 + t;
        const float4 v = ((const float4*)Wo)[i];
        ushort4 o4;
        o4.x = f2bf(v.x); o4.y = f2bf(v.y); o4.z = f2bf(v.z); o4.w = f2bf(v.w);
        ((ushort4*)wo_b)[i] = o4;
    } else {
        const size_t i = (size_t)(bid - 7168) * 256 + t;
        ((float4*)MtF)[i] = float4{0.f, 0.f, 0.f, 0.f};
    }
}

// ---------------------------------------------------------------------------
// Flash-fused attention (R19 verbatim), BK=64 S-steps. 512 blocks, 2 blk/CU.
// LDS 80KB exact: ldsB 2x16KB | ldsZ 2x16KB (prologue: Y) | Pl 16KB swizzled.
// ---------------------------------------------------------------------------
__global__ void __launch_bounds__(256, 2) attn_fused(
    const u16* __restrict__ Y, const u16* __restrict__ xn,
    const u16* __restrict__ Zt, float* __restrict__ opart)
{
    __shared__ u16 ldsB[2][8192];      // 32 KB: slot x (sub0 | sub1)
    __shared__ u16 ldsZ[2][8192];      // 32 KB (prologue: Y tile spans both)
    __shared__ u16 Pl[8192];           // 16 KB swizzled

    const int wgid = blockIdx.x + 32 * blockIdx.y;
    const int xcd = wgid & 7;
    const int p = wgid >> 3;
    const int hb = 2 * xcd + (p & 1);
    const int i0 = (p >> 1) * 64;
    const int h = hb >> 1, b = hb & 1;

    const int t = threadIdx.x;
    const int w = t >> 6, l = t & 63;
    const int wm = w >> 1, wn = w & 1;
    const int lr = l & 15, lk = l >> 4;
    const int sw = lk ^ ((lr >> 1) & 3);

    const u16* Yb = Y + (size_t)(b * 2048 + i0) * 2048 + h * 256;
    const u16* xb = xn + (size_t)b * 2048 * 256;
    const u16* Zb = Zt + (size_t)b * 4194304 + (size_t)h * 524288;

    const int m0 = t >> 2, s0 = t & 3;
    const int c0 = s0 ^ ((m0 >> 1) & 3);
    const int m1 = 64 + m0;
    const int c1 = s0 ^ ((m1 >> 1) & 3);
    const int oB0 = (t & ~63) * 8;
    const int oB1 = (256 + (t & ~63)) * 8;

    const u16 *gZ0, *gZ1, *gZ2, *gZ3;
    const int oZ0 = (t & ~63) * 8;
    const int oZ1 = (256 + (t & ~63)) * 8;
    const int oZ2 = (512 + (t & ~63)) * 8;
    const int oZ3 = (768 + (t & ~63)) * 8;
    {
        const int q0 = t, q1 = 256 + t, q2 = 512 + t, q3 = 768 + t;
        const int mz0 = q0 >> 2, mz1 = q1 >> 2, mz2 = q2 >> 2, mz3 = q3 >> 2;
        const int cz0 = (q0 & 3) ^ ((mz0 >> 1) & 3);
        const int cz1 = (q1 & 3) ^ ((mz1 >> 1) & 3);
        const int cz2 = (q2 & 3) ^ ((mz2 >> 1) & 3);
        const int cz3 = (q3 & 3) ^ ((mz3 >> 1) & 3);
        gZ0 = Zb + (size_t)mz0 * 2048 + cz0 * 8;
        gZ1 = Zb + (size_t)mz1 * 2048 + cz1 * 8;
        gZ2 = Zb + (size_t)mz2 * 2048 + cz2 * 8;
        gZ3 = Zb + (size_t)mz3 * 2048 + cz3 * 8;
    }

#define ISSUE_B_HALF(JBASE, KK, SLOT, SUB)                                            \
    GLDS16(JBASE + (size_t)m0 * 256 + (KK) * 32 + c0 * 8, &ldsB[SLOT][(SUB) * 4096 + oB0]); \
    GLDS16(JBASE + (size_t)m1 * 256 + (KK) * 32 + c1 * 8, &ldsB[SLOT][(SUB) * 4096 + oB1])

#define ISSUE_B2(JBASE, K0, K1, SLOT)                                                 \
    ISSUE_B_HALF(JBASE, K0, SLOT, 0); ISSUE_B_HALF(JBASE, K1, SLOT, 1)

#define ISSUE_Z(OFF, ZBUF)                                                            \
    GLDS16(gZ0 + (OFF), &ldsZ[ZBUF][oZ0]);                                            \
    GLDS16(gZ1 + (OFF), &ldsZ[ZBUF][oZ1]);                                            \
    GLDS16(gZ2 + (OFF), &ldsZ[ZBUF][oZ2]);                                            \
    GLDS16(gZ3 + (OFF), &ldsZ[ZBUF][oZ3])

    // ---- prologue: Y i-tile (32KB) into ldsZ; B(jt0, s0) into ldsB[0] ----
    u16* ldsY = &ldsZ[0][0];
#pragma unroll
    for (int pp = 0; pp < 8; ++pp) {
        const int q = pp * 256 + t;
        const int kt = q >> 8, qq = q & 255;
        const int m = qq >> 2, s = qq & 3;
        const int c = s ^ ((m >> 1) & 3);
        GLDS16(Yb + (size_t)m * 2048 + kt * 32 + c * 8,
               &ldsY[(pp * 256 + (t & ~63)) * 8]);
    }
    ISSUE_B2(xb, 0, 1, 0);
    vm_wait<4>();                      // Y(8) retired; B(4) in flight
    bar();

    bf16x8 yr[8][2];
#pragma unroll
    for (int kt = 0; kt < 8; ++kt)
#pragma unroll
        for (int i = 0; i < 2; ++i)
            yr[kt][i] = *(const bf16x8*)&ldsY[kt * 2048 + (wm * 32 + i * 16 + lr) * 32 + sw * 8];
    lgk0();
    bar();                             // yr reads done before ldsZ overwrite

    f32x4 acc_o[2][8];
#pragma unroll
    for (int i = 0; i < 2; ++i)
#pragma unroll
        for (int j = 0; j < 8; ++j)
            acc_o[i][j] = f32x4{0.f, 0.f, 0.f, 0.f};
    float lsum[8];
#pragma unroll
    for (int i = 0; i < 8; ++i) lsum[i] = 0.f;

#define S_STEP2(KT0, KT1, SLOT, ISSUE)                                                \
    {                                                                                 \
        vm_wait<0>(); bar();                                                          \
        ISSUE;                                                                        \
        {                                                                             \
            bf16x8 bv[4];                                                             \
            _Pragma("unroll")                                                         \
            for (int j = 0; j < 4; ++j)                                               \
                bv[j] = *(const bf16x8*)&ldsB[SLOT][(wn * 64 + j * 16 + lr) * 32 + sw * 8]; \
            __builtin_amdgcn_s_setprio(1);                                            \
            _Pragma("unroll")                                                         \
            for (int j = 0; j < 4; ++j) {                                             \
                acc_s[0][j] = __builtin_amdgcn_mfma_f32_16x16x32_bf16(yr[KT0][0], bv[j], acc_s[0][j], 0, 0, 0); \
                acc_s[1][j] = __builtin_amdgcn_mfma_f32_16x16x32_bf16(yr[KT0][1], bv[j], acc_s[1][j], 0, 0, 0); \
            }                                                                         \
            __builtin_amdgcn_s_setprio(0);                                            \
        }                                                                             \
        {                                                                             \
            bf16x8 bv[4];                                                             \
            _Pragma("unroll")                                                         \
            for (int j = 0; j < 4; ++j)                                               \
                bv[j] = *(const bf16x8*)&ldsB[SLOT][4096 + (wn * 64 + j * 16 + lr) * 32 + sw * 8]; \
            __builtin_amdgcn_s_setprio(1);                                            \
            _Pragma("unroll")                                                         \
            for (int j = 0; j < 4; ++j) {                                             \
                acc_s[0][j] = __builtin_amdgcn_mfma_f32_16x16x32_bf16(yr[KT1][0], bv[j], acc_s[0][j], 0, 0, 0); \
                acc_s[1][j] = __builtin_amdgcn_mfma_f32_16x16x32_bf16(yr[KT1][1], bv[j], acc_s[1][j], 0, 0, 0); \
            }                                                                         \
            __builtin_amdgcn_s_setprio(0);                                            \
        }                                                                             \
    }

#define PV_STEP(KT, VMC, ISSUE)                                                       \
    {                                                                                 \
        vm_wait<VMC>(); bar();                                                        \
        ISSUE;                                                                        \
        const int swz = (lr & 7) * 8;                                                 \
        bf16x8 av0 = *(const bf16x8*)&Pl[(wm * 32 + lr) * 128 + (((KT) * 32 + lk * 8) ^ swz)];      \
        bf16x8 av1 = *(const bf16x8*)&Pl[(wm * 32 + 16 + lr) * 128 + (((KT) * 32 + lk * 8) ^ swz)]; \
        __builtin_amdgcn_s_setprio(1);                                                \
        _Pragma("unroll")                                                             \
        for (int jf = 0; jf < 8; ++jf) {                                              \
            const bf16x8 bz = *(const bf16x8*)&ldsZ[(KT) & 1][(wn * 128 + jf * 16 + lr) * 32 + sw * 8]; \
            acc_o[0][jf] = __builtin_amdgcn_mfma_f32_16x16x32_bf16(av0, bz, acc_o[0][jf], 0, 0, 0);   \
            acc_o[1][jf] = __builtin_amdgcn_mfma_f32_16x16x32_bf16(av1, bz, acc_o[1][jf], 0, 0, 0);   \
        }                                                                             \
        __builtin_amdgcn_s_setprio(0);                                                \
    }

    for (int jt = 0; jt < 16; ++jt) {
        const int j0 = jt * 128;
        const u16* xbj = xb + (size_t)j0 * 256;
        const u16* xbn = xb + (size_t)(((jt + 1) & 15) * 128) * 256;  // wrap: dummy

        f32x4 acc_s[2][4];
#pragma unroll
        for (int i = 0; i < 2; ++i)
#pragma unroll
            for (int j = 0; j < 4; ++j)
                acc_s[i][j] = f32x4{0.f, 0.f, 0.f, 0.f};

        // S phase: 4 merged steps. queues: entering S0: [B_s0(4)]
        S_STEP2(0, 1, 0, ISSUE_B2(xbj, 2, 3, 1))
        S_STEP2(2, 3, 1, ISSUE_B2(xbj, 4, 5, 0))
        S_STEP2(4, 5, 0, ISSUE_B2(xbj, 6, 7, 1))
        S_STEP2(6, 7, 1, ISSUE_Z(j0, 0))
        ISSUE_Z(j0 + 32, 1);           // in-flight entering exp: [Z0(4), Z1(4)]

        // exp + l partials + P -> swizzled Pl[row][col ^ ((row&7)*8)]
#pragma unroll
        for (int i = 0; i < 2; ++i)
#pragma unroll
            for (int j = 0; j < 4; ++j)
#pragma unroll
                for (int r = 0; r < 4; ++r) {
                    const int row = wm * 32 + i * 16 + lk * 4 + r;
                    const int col = wn * 64 + j * 16 + lr;
                    const float e = __expf(acc_s[i][j][r]);
                    lsum[i * 4 + r] += e;
                    Pl[row * 128 + (col ^ ((row & 7) * 8))] = f2bf(e);
                }
        lgk0();                        // Pl writes done; PV0's bar publishes

        // PV queues: entering PV0: [Z0(4), Z1(4)]
        PV_STEP(0, 4, ((void)0))
        PV_STEP(1, 0, ISSUE_Z(j0 + 64, 0))
        PV_STEP(2, 0, ISSUE_Z(j0 + 96, 1); ISSUE_B_HALF(xbn, 0, 0, 0))
        PV_STEP(3, 2, ISSUE_B_HALF(xbn, 1, 0, 1))   // [Z3(4),Bh(2)] -> keep Bh
    }

    // ---- finalize l (bar: all PV3 Pl reads done before aliasing) ----
    bar();
    float* l_lds = (float*)Pl;
    if (t < 64) l_lds[t] = 0.f;
    __syncthreads();
#pragma unroll
    for (int i = 0; i < 2; ++i)
#pragma unroll
        for (int r = 0; r < 4; ++r) {
            float s = lsum[i * 4 + r];
            s += __shfl_xor(s, 1, 64);
            s += __shfl_xor(s, 2, 64);
            s += __shfl_xor(s, 4, 64);
            s += __shfl_xor(s, 8, 64);
            if (lr == 0) atomicAdd(&l_lds[wm * 32 + i * 16 + lk * 4 + r], s);
        }
    __syncthreads();

    // ---- scale by 1/l, plain-store per-head partial ----
    float* oh = opart + (size_t)h * 1048576;
#pragma unroll
    for (int i = 0; i < 2; ++i)
#pragma unroll
        for (int r = 0; r < 4; ++r) {
            const int row = wm * 32 + i * 16 + lk * 4 + r;
            const float rl = 1.0f / l_lds[row];
            float* orow = oh + (size_t)(b * 2048 + i0 + row) * 256 + wn * 128;
#pragma unroll
            for (int jf = 0; jf < 8; ++jf)
                orow[jf * 16 + lr] = acc_o[i][jf][r] * rl;
        }
}

// ---------------------------------------------------------------------------
// Head reduction: out[i] = sum_h opart[h][i].
// ---------------------------------------------------------------------------
__global__ void __launch_bounds__(256) hreduce_kernel(const float* __restrict__ opart,
                                                      float* __restrict__ out)
{
    const size_t i = (size_t)blockIdx.x * 256 + threadIdx.x;
    float4 s = ((const float4*)opart)[i];
#pragma unroll
    for (int h = 1; h < 8; ++h) {
        const float4 v = ((const float4*)(opart + (size_t)h * 1048576))[i];
        s.x += v.x; s.y += v.y; s.z += v.z; s.w += v.w;
    }
    ((float4*)out)[i] = s;
}

__global__ void __launch_bounds__(256) cast_bf16_kernel(const float* __restrict__ src,
                                                        u16* __restrict__ dst, float scale)
{
    const size_t i = (size_t)blockIdx.x * 256 + threadIdx.x;
    const float4 v = ((const float4*)src)[i];
    ushort4 o4;
    o4.x = f2bf(v.x * scale);
    o4.y = f2bf(v.y * scale);
    o4.z = f2bf(v.z * scale);
    o4.w = f2bf(v.w * scale);
    ((ushort4*)dst)[i] = o4;
}

extern "C" void kernel_launch(void* const* d_in, const int* in_sizes, int n_in,
                              void* d_out, int out_size, void* d_ws, size_t ws_size,
                              hipStream_t stream)
{
    (void)in_sizes; (void)n_in; (void)ws_size; (void)out_size;
    const float* x     = (const float*)d_in[0];
    const float* gamma = (const float*)d_in[1];
    const float* Wq    = (const float*)d_in[2];
    const float* Wk    = (const float*)d_in[3];
    const float* Wv    = (const float*)d_in[4];
    const float* Wo    = (const float*)d_in[5];
    float* out = (float*)d_out;

    char* ws = (char*)d_ws;
    const size_t MB = 1048576;
    u16* wqt   = (u16*)(ws);             // [3][8][256][2048] bf16 (SCALE folded in Wq)
    u16* wkt   = (u16*)(ws + 8 * MB);
    u16* wvt   = (u16*)(ws + 16 * MB);
    u16* wo    = (u16*)(ws + 24 * MB);   // [256][16384] bf16
    u16* xn    = (u16*)(ws + 32 * MB);   // [4096][256] bf16
    u16* Mt    = (u16*)(ws + 34 * MB);   // [8*256][256] bf16
    u16* Nb    = (u16*)(ws + 35 * MB);   // [8*256][256] bf16
    float* MtF = (float*)(ws + 36 * MB); // fp32 split-K accum: Mt (2MB) + Nb (2MB)
    u16* Y     = (u16*)(ws + 44 * MB);   // [4096][2048] bf16
    u16* Zt    = (u16*)(ws + 60 * MB);   // [2][2048][2048] bf16
    float* opart = (float*)(ws);         // [8][4096][256] fp32 (reuses 0..32MB)

    // 1. fused prologue: tcast3 + cast_wo + zero(MtF)
    prep_kernel<<<8192, 256, 0, stream>>>(Wq, Wk, Wv, Wo, wqt, wo, MtF);

    // 2. weight GEMMs (split-K x4, fp32 atomics; R16-best) + co-dispatched ln
    gemm_w<<<dim3(2, 2, 320), 256, 0, stream>>>(wkt, wqt, wo, wvt, MtF, x, gamma, xn);

    // 3. cast MtF+NbF -> Mt+Nb bf16
    cast_bf16_kernel<<<1024, 256, 0, stream>>>(MtF, Mt, 1.0f);

    // 4. Y = xn.Mt^T and Zt = Nb.xn^T
    gemm_yz<<<dim3(16, 16, 4), 256, 0, stream>>>(xn, Mt, Nb, Y, Zt);

    // 5. fused S -> softmax -> PV -> per-head partial stores
    attn_fused<<<dim3(32, 16), 256, 0, stream>>>(Y, xn, Zt, opart);

    // 6. head-sum reduction
    hreduce_kernel<<<1024, 256, 0, stream>>>(opart, out);
}